// Round 1
// baseline (471.660 us; speedup 1.0000x reference)
//
#include <hip/hip_runtime.h>

// Dims fixed by the problem: L=13, B=16, S=512, D=768, W=256.
#define L_DIM 13
#define B_DIM 16
#define S_DIM 512
#define D_DIM 768
#define W_DIM 256

// One block per (l, b, w). 192 threads: each thread owns one float4 (4 floats)
// of the D=768 output row (192 * 4 = 768). segment_ids is sorted per sentence,
// so word w's subwords are the contiguous span [lower_bound(w), lower_bound(w+1)).
// The binary search is block-uniform (same for all lanes -> no divergence) and
// hits L1/L2 (each 2KB seg row is shared by L*W = 3328 blocks).
__global__ __launch_bounds__(192) void segpool_kernel(
    const float* __restrict__ hs,   // [L, B, S, D]
    const int* __restrict__ seg,    // [B, S], sorted ascending per row
    float* __restrict__ out)        // [L, B, W, D]
{
    const int w = blockIdx.x;
    const int b = blockIdx.y;
    const int l = blockIdx.z;

    const int* srow = seg + b * S_DIM;

    // start = first s with srow[s] >= w
    int lo = 0, hi = S_DIM;
    while (lo < hi) {
        int mid = (lo + hi) >> 1;
        if (srow[mid] < w) lo = mid + 1; else hi = mid;
    }
    const int start = lo;
    // end = first s with srow[s] >= w+1 (resume from start)
    hi = S_DIM;
    while (lo < hi) {
        int mid = (lo + hi) >> 1;
        if (srow[mid] < w + 1) lo = mid + 1; else hi = mid;
    }
    const int end = lo;

    const int t = threadIdx.x;  // 0..191, float4 lane within the row
    const float4* __restrict__ base =
        (const float4*)(hs + ((size_t)l * B_DIM + b) * (size_t)S_DIM * D_DIM);

    float4 acc = make_float4(0.f, 0.f, 0.f, 0.f);
    for (int s = start; s < end; ++s) {
        float4 v = base[(size_t)s * (D_DIM / 4) + t];
        acc.x += v.x; acc.y += v.y; acc.z += v.z; acc.w += v.w;
    }

    // Always write (zeros for empty words) — output is re-poisoned to 0xAA
    // before every timed launch, so every element must be written.
    float4* __restrict__ orow =
        (float4*)(out + (((size_t)l * B_DIM + b) * (size_t)W_DIM + w) * D_DIM);
    orow[t] = acc;
}

extern "C" void kernel_launch(void* const* d_in, const int* in_sizes, int n_in,
                              void* d_out, int out_size, void* d_ws, size_t ws_size,
                              hipStream_t stream) {
    const float* hs  = (const float*)d_in[0];   // hidden_states [L,B,S,D] f32
    const int*   seg = (const int*)d_in[1];     // segment_ids [B,S] i32
    // d_in[2] = num_words (scalar 256) — compile-time constant W_DIM.
    float* out = (float*)d_out;                 // [L,B,W,D] f32

    dim3 grid(W_DIM, B_DIM, L_DIM);             // 256 * 16 * 13 = 53248 blocks
    segpool_kernel<<<grid, 192, 0, stream>>>(hs, seg, out);
}

// Round 2
// 459.396 us; speedup vs baseline: 1.0267x; 1.0267x over previous
//
#include <hip/hip_runtime.h>

// Dims fixed by the problem: L=13, B=16, S=512, D=768, W=256.
#define L_DIM 13
#define B_DIM 16
#define S_DIM 512
#define D_DIM 768
#define W_DIM 256

typedef float v4f __attribute__((ext_vector_type(4)));

// Kernel A: precompute word spans. For each (b, w), binary-search the sorted
// seg row for [start, end). 4096 entries -> int2 table in d_ws. Runs in ~2 µs;
// removes the 18-dependent-load search chain from all 53248 main blocks.
// (d_ws is re-poisoned to 0xAA before every launch, so this must run each call.)
__global__ __launch_bounds__(256) void span_kernel(
    const int* __restrict__ seg,    // [B, S] sorted ascending per row
    int2* __restrict__ spans)       // [B, W]
{
    const int idx = blockIdx.x * 256 + threadIdx.x;   // 0 .. B*W-1
    const int b = idx >> 8;                           // idx / W_DIM
    const int w = idx & (W_DIM - 1);
    const int* srow = seg + b * S_DIM;

    int lo = 0, hi = S_DIM;
    while (lo < hi) { int m = (lo + hi) >> 1; if (srow[m] < w) lo = m + 1; else hi = m; }
    const int start = lo;
    hi = S_DIM;
    while (lo < hi) { int m = (lo + hi) >> 1; if (srow[m] < w + 1) lo = m + 1; else hi = m; }
    spans[idx] = make_int2(start, lo);
}

// Kernel B: one block per (l, b, w); 192 threads * float4 = the D=768 row.
// Streamed traffic (hidden_states read-once, out write-once) is non-temporal
// so it doesn't evict the hot span table / seg rows from L2.
__global__ __launch_bounds__(192) void segpool_kernel(
    const float* __restrict__ hs,     // [L, B, S, D]
    const int2* __restrict__ spans,   // [B, W]
    float* __restrict__ out)          // [L, B, W, D]
{
    const int w = blockIdx.x;
    const int b = blockIdx.y;
    const int l = blockIdx.z;

    const int2 se = spans[b * W_DIM + w];   // block-uniform 8B cached load

    const int t = threadIdx.x;  // 0..191, float4 lane within the row
    const v4f* __restrict__ base =
        (const v4f*)(hs + ((size_t)l * B_DIM + b) * (size_t)S_DIM * D_DIM);

    v4f acc = {0.f, 0.f, 0.f, 0.f};
    for (int s = se.x; s < se.y; ++s) {
        v4f v = __builtin_nontemporal_load(&base[(size_t)s * (D_DIM / 4) + t]);
        acc += v;
    }

    // Always write (zeros for empty words) — d_out is re-poisoned each launch.
    v4f* __restrict__ orow =
        (v4f*)(out + (((size_t)l * B_DIM + b) * (size_t)W_DIM + w) * D_DIM);
    __builtin_nontemporal_store(acc, &orow[t]);
}

extern "C" void kernel_launch(void* const* d_in, const int* in_sizes, int n_in,
                              void* d_out, int out_size, void* d_ws, size_t ws_size,
                              hipStream_t stream) {
    const float* hs  = (const float*)d_in[0];   // hidden_states [L,B,S,D] f32
    const int*   seg = (const int*)d_in[1];     // segment_ids [B,S] i32
    float* out  = (float*)d_out;                // [L,B,W,D] f32
    int2*  spans = (int2*)d_ws;                 // [B,W] = 32 KB scratch

    span_kernel<<<(B_DIM * W_DIM) / 256, 256, 0, stream>>>(seg, spans);

    dim3 grid(W_DIM, B_DIM, L_DIM);             // 53248 blocks
    segpool_kernel<<<grid, 192, 0, stream>>>(hs, spans, out);
}